// Round 12
// baseline (315.459 us; speedup 1.0000x reference)
//
#include <hip/hip_runtime.h>

// Problem constants
constexpr int BATCH = 8;
constexpr int NPT   = 8192;   // N points
constexpr int NSMP  = 2048;   // S sampled points
constexpr int D1C   = 128;    // skip feature channels
constexpr int D2C   = 256;    // sampled feature channels
constexpr int CIN   = 384;    // D1C + D2C
constexpr int C1    = 256;    // layer-1 out channels
constexpr int C2    = 128;    // layer-2 out channels
constexpr int BN_TOTAL = BATCH * NPT;  // 65536 rows

constexpr int BM = 128, BK = 32;
constexpr int NRB = BN_TOTAL / BM;   // 512 row-blocks

typedef __bf16 bf16x8 __attribute__((ext_vector_type(8)));
typedef short  s16x8  __attribute__((ext_vector_type(8)));
typedef float  f32x4  __attribute__((ext_vector_type(4)));
typedef unsigned short u16x4 __attribute__((ext_vector_type(4)));

__device__ __forceinline__ unsigned short f2bf(float x) {
  unsigned u = __builtin_bit_cast(unsigned, x);
  u += 0x7fffu + ((u >> 16) & 1u);   // round-to-nearest-even
  return (unsigned short)(u >> 16);
}
__device__ __forceinline__ float bf2f(unsigned short h) {
  return __builtin_bit_cast(float, (unsigned)h << 16);
}

// async global -> LDS, 16 B per lane; lds dest wave-uniform base + lane*16
__device__ __forceinline__ void gld_lds16(const void* g, void* l) {
  __builtin_amdgcn_global_load_lds(
      (const __attribute__((address_space(1))) void*)g,
      (__attribute__((address_space(3))) void*)l, 16, 0, 0);
}

// ---------------------------------------------------------------------------
// prep_all: fused transpose(sfeat->sfeatT) + skip->featB + W casts + spos pack
// + BN-stat zeroing. Role selected by block-index range.
// R5 lesson: NO __threadfence cross-block reductions on CDNA4; BN stats go
// through device-scope float atomics (G12).
// ---------------------------------------------------------------------------
constexpr int PT_T = (NSMP / 32) * (D2C / 32) * BATCH;  // 4096 transpose blocks
constexpr int PT_S = (NPT / 32) * (D1C / 32) * BATCH;   // 8192 skip blocks
constexpr int PT_M = (C1 * CIN + 255) / 256;            // 384 misc blocks

__global__ __launch_bounds__(256) void prep_all(
    const float* __restrict__ sfeat, float* __restrict__ sfeatT,
    const float* __restrict__ skip, unsigned short* __restrict__ featB,
    const float* __restrict__ spos, float* __restrict__ sposI,
    float4* __restrict__ qs4,
    const float* __restrict__ W1, unsigned short* __restrict__ W1h,
    const float* __restrict__ W2, unsigned short* __restrict__ W2h,
    float* __restrict__ stats) {
  __shared__ float tile[32][33];
  int bid = blockIdx.x, tid = threadIdx.x;
  int tx = tid & 31, ty = tid >> 5;
  if (bid < PT_T) {
    int z = bid >> 9;
    int r = bid & 511;
    int c0 = (r & 63) * 32;     // over NSMP
    int r0 = (r >> 6) * 32;     // over D2C
    const float* inb = sfeat + (size_t)z * D2C * NSMP;
    float* outb = sfeatT + (size_t)z * NSMP * D2C;
#pragma unroll
    for (int i = 0; i < 32; i += 8)
      tile[ty + i][tx] = inb[(size_t)(r0 + ty + i) * NSMP + c0 + tx];
    __syncthreads();
#pragma unroll
    for (int i = 0; i < 32; i += 8)
      outb[(size_t)(c0 + ty + i) * D2C + r0 + tx] = tile[tx][ty + i];
  } else if (bid < PT_T + PT_S) {
    int id = bid - PT_T;
    int z = id >> 10;
    int r = id & 1023;
    int n0 = (r & 255) * 32;    // over NPT
    int d0 = (r >> 8) * 32;     // over D1C
#pragma unroll
    for (int i = 0; i < 32; i += 8)
      tile[ty + i][tx] = skip[((size_t)z * D1C + d0 + ty + i) * NPT + n0 + tx];
    __syncthreads();
#pragma unroll
    for (int i = 0; i < 32; i += 8) {
      int n = n0 + ty + i;
      featB[((size_t)z * NPT + n) * CIN + d0 + tx] = f2bf(tile[tx][ty + i]);
    }
  } else {
    int g = (bid - PT_T - PT_S) * 256 + tid;
    if (g < 768) stats[g] = 0.f;
    if (g < C1 * CIN) W1h[g] = f2bf(W1[g]);
    if (g < C2 * C1)  W2h[g] = f2bf(W2[g]);
    if (g < BATCH * NSMP) {
      int b = g >> 11, s = g & (NSMP - 1);
      const float* sp = spos + (size_t)b * 3 * NSMP;
      float x = sp[s], y = sp[NSMP + s], z = sp[2 * NSMP + s];
      sposI[(size_t)g * 3 + 0] = x;
      sposI[(size_t)g * 3 + 1] = y;
      sposI[(size_t)g * 3 + 2] = z;
      qs4[g] = make_float4(-2.f * x, -2.f * y, -2.f * z,
                           fmaf(x, x, fmaf(y, y, z * z)));
    }
  }
}

// ---------------------------------------------------------------------------
// knn_scan (R9/R11 verbatim, known-good): PURE scan, no phases.
// 256 blocks x 512 thr; block owns 256 points, 4 pts/lane. LDS candidate
// broadcast (R4 TA lesson), XCD swizzle b=blk&7 (R7), +pp recenter (R2).
// Per-wave top-4 -> global mkG[32 planes][BN_TOTAL], coalesced.
// ---------------------------------------------------------------------------
constexpr int KWAVES = 8;
constexpr int SEGK = NSMP / KWAVES;  // 256 candidates per wave

__device__ __forceinline__ void ins_med3(float kf, float& k0, float& k1,
                                         float& k2, float& k3) {
  float o0 = k0, o1 = k1, o2 = k2;
  k0 = fminf(kf, o0);
  k1 = __builtin_amdgcn_fmed3f(kf, o0, o1);
  k2 = __builtin_amdgcn_fmed3f(kf, o1, o2);
  k3 = __builtin_amdgcn_fmed3f(kf, o2, k3);
}

__global__ __launch_bounds__(512, 2) void knn_scan(
    const float* __restrict__ pos,    // [B,3,NPT]
    const float4* __restrict__ qs4g,  // [B,NSMP] transformed
    float* __restrict__ mkG) {        // [32 planes][BN_TOTAL]
  __shared__ __align__(16) float4 qs[NSMP];  // 32 KB

  int tid = threadIdx.x;
  int wave = tid >> 6, lane = tid & 63;
  int blk = blockIdx.x;
  int b = blk & 7;               // XCD swizzle: batch b -> XCD b
  int n0 = (blk >> 3) << 8;      // 32 chunks of 256 points per batch

  const float* pb = pos + (size_t)b * 3 * NPT;
  float px[4], py[4], pz[4], pp[4];
#pragma unroll
  for (int m = 0; m < 4; m++) {
    int n = n0 + (m << 6) + lane;
    px[m] = pb[n]; py[m] = pb[NPT + n]; pz[m] = pb[2 * NPT + n];
    pp[m] = fmaf(px[m], px[m], fmaf(py[m], py[m], pz[m] * pz[m]));
  }

  const float INF = __builtin_inff();
  float k0[4], k1[4], k2[4], k3[4];
#pragma unroll
  for (int m = 0; m < 4; m++) { k0[m] = INF; k1[m] = INF; k2[m] = INF; k3[m] = INF; }

  int s0 = wave * SEGK;
  const float4* qsrc = qs4g + (size_t)b * NSMP;
#pragma unroll
  for (int r = 0; r < 4; r++)
    gld_lds16(&qsrc[s0 + r * 64 + lane], &qs[s0 + r * 64]);
  __syncthreads();

#define KSTEP4(Q, SS)                                                        \
  {                                                                          \
    _Pragma("unroll")                                                        \
    for (int m_ = 0; m_ < 4; m_++) {                                         \
      float tt = (Q).w + pp[m_];  /* recenter: d small near neighbors */     \
      float d_ = fmaf(px[m_], (Q).x,                                         \
                      fmaf(py[m_], (Q).y, fmaf(pz[m_], (Q).z, tt)));         \
      unsigned ki_ = (__builtin_bit_cast(unsigned, d_) & 0xFFFFF800u) |      \
                     (unsigned)(SS);                                         \
      ins_med3(__builtin_bit_cast(float, ki_), k0[m_], k1[m_], k2[m_], k3[m_]); \
    }                                                                        \
  }

  for (int t = 0; t < SEGK; t += 8) {
    float4 qv[8];
#pragma unroll
    for (int u = 0; u < 8; u++) qv[u] = qs[s0 + t + u];  // broadcast ds_read
#pragma unroll
    for (int u = 0; u < 8; u++) KSTEP4(qv[u], s0 + t + u)
  }
#undef KSTEP4

  // write per-wave top-4 to global planes, coalesced (lane -> point)
  size_t gbase = (size_t)b * NPT + n0 + lane;
#pragma unroll
  for (int m = 0; m < 4; m++) {
    size_t gp = gbase + (m << 6);
    mkG[(size_t)(wave * 4 + 0) * BN_TOTAL + gp] = k0[m];
    mkG[(size_t)(wave * 4 + 1) * BN_TOTAL + gp] = k1[m];
    mkG[(size_t)(wave * 4 + 2) * BN_TOTAL + gp] = k2[m];
    mkG[(size_t)(wave * 4 + 3) * BN_TOTAL + gp] = k3[m];
  }
}

// ---------------------------------------------------------------------------
// knn_post v3 — WAVE-AUTONOMOUS, zero block barriers (R11 lesson: v2 was
// still a __syncthreads convoy — VALUBusy 8.4%, Occ 15%; all waves drained
// at每 phase). Each wave owns 16 points end-to-end:
//  - merge: lane=(g=lane>>4, pt=lane&15); 8 NAMED plane loads pre-issued,
//    sorted-insert, then shfl_xor(16,32) butterfly -> all lanes converge to
//    the point's final top-4 (planes partition candidates; keys unique).
//  - cert + fp64 weights computed by all 4 lanes/point (no divergence);
//    g==0 lanes write il/wl to the wave's LDS slot (wave-internal order).
//  - fallback via __ballot mask (uniform), whole-wave rescan per flagged pt.
//  - interp: 2 pts/iter, 6 pre-issued gathers (R3 lesson).
// 1024 blocks x 256 thr; waves independent -> 16 streaming waves/CU.
// ---------------------------------------------------------------------------
__device__ __forceinline__ bool dless(double d, int i, double D, int I) {
  return d < D || (d == D && i < I);
}
__device__ __forceinline__ void dins3(double d, int i,
                                      double& b0, double& b1, double& b2,
                                      int& i0, int& i1, int& i2) {
  if (dless(d, i, b2, i2)) {
    if (dless(d, i, b1, i1)) {
      b2 = b1; i2 = i1;
      if (dless(d, i, b0, i0)) { b1 = b0; i1 = i0; b0 = d; i0 = i; }
      else                     { b1 = d; i1 = i; }
    } else { b2 = d; i2 = i; }
  }
}

constexpr int PPW = 16;  // points per wave

__global__ __launch_bounds__(256) void knn_post(
    const float* __restrict__ pos,
    const float* __restrict__ sposI,
    const float* __restrict__ mkG,
    const float* __restrict__ sfeatT,
    unsigned short* __restrict__ featB) {
  __shared__ int   il[4][PPW][3];
  __shared__ float wl[4][PPW][3];

  int tid = threadIdx.x;
  int wave = tid >> 6, lane = tid & 63;
  int blk = blockIdx.x;
  int b = blk & 7;                       // XCD swizzle, matches knn_scan
  int chunk = (blk >> 3) * 4 + wave;     // 512 chunks of 16 points per batch
  int n0 = chunk * PPW;

  int g  = lane >> 4;    // plane group 0..3 (planes 8g..8g+7)
  int pt = lane & 15;    // point within wave
  int n  = n0 + pt;
  size_t gp = (size_t)b * NPT + n;

  const float* pb = pos + (size_t)b * 3 * NPT;
  const float INF = __builtin_inff();

  // ---- 8 pre-issued plane loads, then insert (no serial load-use) ----
  float v0 = mkG[(size_t)(g * 8 + 0) * BN_TOTAL + gp];
  float v1 = mkG[(size_t)(g * 8 + 1) * BN_TOTAL + gp];
  float v2 = mkG[(size_t)(g * 8 + 2) * BN_TOTAL + gp];
  float v3 = mkG[(size_t)(g * 8 + 3) * BN_TOTAL + gp];
  float v4 = mkG[(size_t)(g * 8 + 4) * BN_TOTAL + gp];
  float v5 = mkG[(size_t)(g * 8 + 5) * BN_TOTAL + gp];
  float v6 = mkG[(size_t)(g * 8 + 6) * BN_TOTAL + gp];
  float v7 = mkG[(size_t)(g * 8 + 7) * BN_TOTAL + gp];
  float K0 = INF, K1 = INF, K2 = INF, K3 = INF;
  ins_med3(v0, K0, K1, K2, K3); ins_med3(v1, K0, K1, K2, K3);
  ins_med3(v2, K0, K1, K2, K3); ins_med3(v3, K0, K1, K2, K3);
  ins_med3(v4, K0, K1, K2, K3); ins_med3(v5, K0, K1, K2, K3);
  ins_med3(v6, K0, K1, K2, K3); ins_med3(v7, K0, K1, K2, K3);

  // ---- butterfly merge across the 4 groups (lanes pt, pt+16, pt+32, pt+48)
#pragma unroll
  for (int mask = 16; mask <= 32; mask <<= 1) {
    float o0 = __shfl_xor(K0, mask, 64);
    float o1 = __shfl_xor(K1, mask, 64);
    float o2 = __shfl_xor(K2, mask, 64);
    float o3 = __shfl_xor(K3, mask, 64);
    ins_med3(o0, K0, K1, K2, K3); ins_med3(o1, K0, K1, K2, K3);
    ins_med3(o2, K0, K1, K2, K3); ins_med3(o3, K0, K1, K2, K3);
  }

  // ---- cert + fp64 weights (all 4 lanes per point, redundant, uniform) ----
  int I0 = (int)(__builtin_bit_cast(unsigned, K0) & 0x7FFu);
  int I1 = (int)(__builtin_bit_cast(unsigned, K1) & 0x7FFu);
  int I2 = (int)(__builtin_bit_cast(unsigned, K2) & 0x7FFu);
  float d2m = __builtin_bit_cast(float, __builtin_bit_cast(unsigned, K2) & 0xFFFFF800u);
  float d3m = __builtin_bit_cast(float, __builtin_bit_cast(unsigned, K3) & 0xFFFFF800u);
  bool flag = (d3m - d2m) < 2e-3f * fmaxf(d3m, 0.f) + 1e-5f;

  {
    const float* q = sposI + (size_t)b * 3 * NSMP;
    double pxd = (double)pb[n], pyd = (double)pb[NPT + n], pzd = (double)pb[2 * NPT + n];
    double dd[3]; int II[3] = {I0, I1, I2};
#pragma unroll
    for (int k = 0; k < 3; k++) {
      double dx = pxd - (double)q[3 * II[k]];
      double dy = pyd - (double)q[3 * II[k] + 1];
      double dz = pzd - (double)q[3 * II[k] + 2];
      dd[k] = dx * dx + dy * dy + dz * dz;
    }
    double w0 = 1.0 / (dd[0] + 1e-8);
    double w1 = 1.0 / (dd[1] + 1e-8);
    double w2 = 1.0 / (dd[2] + 1e-8);
    double inv = 1.0 / (w0 + w1 + w2);
    if (g == 0) {
      il[wave][pt][0] = I0; il[wave][pt][1] = I1; il[wave][pt][2] = I2;
      wl[wave][pt][0] = (float)(w0 * inv);
      wl[wave][pt][1] = (float)(w1 * inv);
      wl[wave][pt][2] = (float)(w2 * inv);
    }
  }

  // ---- exact fp64 fallback, whole wave per flagged point (uniform mask) ----
  unsigned long long fm = __ballot(flag) & 0xFFFFull;  // dedupe: g==0 slots
  while (fm) {
    int P = __ffsll(fm) - 1;
    fm &= fm - 1;
    int nf = n0 + P;
    double pxd = (double)pb[nf], pyd = (double)pb[NPT + nf], pzd = (double)pb[2 * NPT + nf];
    const float* q = sposI + (size_t)b * 3 * NSMP;
    double b0 = 1e300, b1 = 1e300, b2 = 1e300;
    int i0 = 0x7FFFFFFF, i1 = 0x7FFFFFFF, i2 = 0x7FFFFFFF;
    for (int s = lane; s < NSMP; s += 64) {
      double dx = pxd - (double)q[3 * s];
      double dy = pyd - (double)q[3 * s + 1];
      double dz = pzd - (double)q[3 * s + 2];
      double d = dx * dx + dy * dy + dz * dz;
      dins3(d, s, b0, b1, b2, i0, i1, i2);
    }
#pragma unroll
    for (int m = 1; m < 64; m <<= 1) {
      double o0 = __shfl_xor(b0, m, 64), o1 = __shfl_xor(b1, m, 64), o2 = __shfl_xor(b2, m, 64);
      int    j0 = __shfl_xor(i0, m, 64), j1 = __shfl_xor(i1, m, 64), j2 = __shfl_xor(i2, m, 64);
      dins3(o0, j0, b0, b1, b2, i0, i1, i2);
      dins3(o1, j1, b0, b1, b2, i0, i1, i2);
      dins3(o2, j2, b0, b1, b2, i0, i1, i2);
    }
    if (lane == 0) {
      double w0 = 1.0 / (b0 + 1e-8);
      double w1 = 1.0 / (b1 + 1e-8);
      double w2 = 1.0 / (b2 + 1e-8);
      double inv = 1.0 / (w0 + w1 + w2);
      il[wave][P][0] = i0; il[wave][P][1] = i1; il[wave][P][2] = i2;
      wl[wave][P][0] = (float)(w0 * inv);
      wl[wave][P][1] = (float)(w1 * inv);
      wl[wave][P][2] = (float)(w2 * inv);
    }
  }

  // ---- interp: 16 points, 2/iter with 6 pre-issued gathers ----
  const float* base = sfeatT + (size_t)b * NSMP * D2C;
  for (int i = 0; i < PPW; i += 2) {
    int P0 = i, P1 = i + 1;
    int a0 = il[wave][P0][0], a1 = il[wave][P0][1], a2 = il[wave][P0][2];
    int c0 = il[wave][P1][0], c1 = il[wave][P1][1], c2 = il[wave][P1][2];
    float aw0 = wl[wave][P0][0], aw1 = wl[wave][P0][1], aw2 = wl[wave][P0][2];
    float cw0 = wl[wave][P1][0], cw1 = wl[wave][P1][1], cw2 = wl[wave][P1][2];
    float4 u0 = *(const float4*)&base[(size_t)a0 * D2C + (lane << 2)];
    float4 u1 = *(const float4*)&base[(size_t)a1 * D2C + (lane << 2)];
    float4 u2 = *(const float4*)&base[(size_t)a2 * D2C + (lane << 2)];
    float4 v0f = *(const float4*)&base[(size_t)c0 * D2C + (lane << 2)];
    float4 v1f = *(const float4*)&base[(size_t)c1 * D2C + (lane << 2)];
    float4 v2f = *(const float4*)&base[(size_t)c2 * D2C + (lane << 2)];
    u16x4 o0, o1;
    o0[0] = f2bf(aw0 * u0.x + aw1 * u1.x + aw2 * u2.x);
    o0[1] = f2bf(aw0 * u0.y + aw1 * u1.y + aw2 * u2.y);
    o0[2] = f2bf(aw0 * u0.z + aw1 * u1.z + aw2 * u2.z);
    o0[3] = f2bf(aw0 * u0.w + aw1 * u1.w + aw2 * u2.w);
    o1[0] = f2bf(cw0 * v0f.x + cw1 * v1f.x + cw2 * v2f.x);
    o1[1] = f2bf(cw0 * v0f.y + cw1 * v1f.y + cw2 * v2f.y);
    o1[2] = f2bf(cw0 * v0f.z + cw1 * v1f.z + cw2 * v2f.z);
    o1[3] = f2bf(cw0 * v0f.w + cw1 * v1f.w + cw2 * v2f.w);
    *(u16x4*)&featB[((size_t)b * NPT + n0 + P0) * CIN + D1C + (lane << 2)] = o0;
    *(u16x4*)&featB[((size_t)b * NPT + n0 + P1) * CIN + D1C + (lane << 2)] = o1;
  }
}

// ---------------------------------------------------------------------------
// GEMM1 (R10 version, measured-neutral): 8-wave 128x256 full-width tile.
// featB read once per row-tile. BN1 stats via device-scope float atomics.
// ---------------------------------------------------------------------------
__global__ __launch_bounds__(512) void gemm1_mw(
    const unsigned short* __restrict__ featB,  // [BN_TOTAL][CIN] bf16
    const unsigned short* __restrict__ W1h,    // [C1][CIN] bf16
    const float* __restrict__ bias,
    unsigned short* __restrict__ Y1,           // [BN_TOTAL][C1] bf16
    float* __restrict__ sum1,                  // [C1]
    float* __restrict__ sumsq1) {              // [C1]
  __shared__ __align__(16) unsigned short As[BM * BK];  // 8 KB
  __shared__ __align__(16) unsigned short Bs[C1 * BK];  // 16 KB
  int tid = threadIdx.x;
  int lane = tid & 63, w = tid >> 6;
  int wr = w >> 2, wc = w & 3;
  int m16 = lane & 15, quad = lane >> 4;
  int rb = blockIdx.x;
  int row0 = rb * BM;
  int srow = lane >> 2, scol8 = (lane & 3) * 8;

  f32x4 acc[4][4];
#pragma unroll
  for (int j = 0; j < 4; j++) {
    float bj = bias[wc * 64 + j * 16 + m16];
#pragma unroll
    for (int i = 0; i < 4; i++) acc[i][j] = f32x4{bj, bj, bj, bj};
  }

  for (int k0 = 0; k0 < CIN; k0 += BK) {
    {  // A tile: 128x32, one round (8 waves x 16 rows)
      int lb = __builtin_amdgcn_readfirstlane((w * 16) * BK);
      gld_lds16(&featB[(size_t)(row0 + w * 16 + srow) * CIN + k0 + scol8],
                &As[lb]);
    }
#pragma unroll
    for (int rr = 0; rr < 2; rr++) {  // B tile: 256x32, two rounds
      int lb = __builtin_amdgcn_readfirstlane((rr * 128 + w * 16) * BK);
      gld_lds16(&W1h[(size_t)(rr * 128 + w * 16 + srow) * CIN + k0 + scol8],
                &Bs[lb]);
    }
    __syncthreads();

    bf16x8 a[4], bb[4];
#pragma unroll
    for (int i = 0; i < 4; i++)
      a[i] = __builtin_bit_cast(bf16x8,
          *(const s16x8*)&As[(wr * 64 + i * 16 + m16) * BK + quad * 8]);
#pragma unroll
    for (int j = 0; j < 4; j++)
      bb[j] = __builtin_bit_cast(bf16x8,
          *(const s16x8*)&Bs[(wc * 64 + j * 16 + m16) * BK + quad * 8]);
#pragma unroll
    for (int i = 0; i < 4; i++)
#pragma unroll
      for (int j = 0; j < 4; j++)
        acc[i][j] = __builtin_amdgcn_mfma_f32_16x16x32_bf16(a[i], bb[j], acc[i][j], 0, 0, 0);
    __syncthreads();
  }

#pragma unroll
  for (int j = 0; j < 4; j++) {
    int col = wc * 64 + j * 16 + m16;
    float s = 0.f, q = 0.f;
#pragma unroll
    for (int i = 0; i < 4; i++)
#pragma unroll
      for (int r = 0; r < 4; r++) {
        float v = acc[i][j][r];
        Y1[(size_t)(row0 + wr * 64 + i * 16 + quad * 4 + r) * C1 + col] = f2bf(v);
        s += v; q = fmaf(v, v, q);
      }
    s += __shfl_xor(s, 16, 64); s += __shfl_xor(s, 32, 64);
    q += __shfl_xor(q, 16, 64); q += __shfl_xor(q, 32, 64);
    if (quad == 0) {
      atomicAdd(&sum1[col], s);
      atomicAdd(&sumsq1[col], q);
    }
  }
}

// ---------------------------------------------------------------------------
// GEMM2, 4-wave 128x128 tile: X2 = relu(bn1(Y1)) fused in reg-staged A.
// BN1 coefficients computed in-kernel from atomic sums (stream order).
// BN2 stats via atomics. grid = NRB.
// ---------------------------------------------------------------------------
__global__ __launch_bounds__(256) void gemm2_mw(
    const unsigned short* __restrict__ Y1,   // [BN_TOTAL][C1] bf16
    const float* __restrict__ g1, const float* __restrict__ beta1,
    const float* __restrict__ sum1, const float* __restrict__ sumsq1,
    const unsigned short* __restrict__ W2h,  // [C2][C1] bf16
    const float* __restrict__ bias,
    unsigned short* __restrict__ Y2,         // [BN_TOTAL][C2] bf16
    float* __restrict__ sum2, float* __restrict__ sumsq2) {
  __shared__ __align__(16) unsigned short As[BM * BK];
  __shared__ __align__(16) unsigned short Bs[BM * BK];
  __shared__ float scs[C1], shs[C1];
  int tid = threadIdx.x;
  int lane = tid & 63, w = tid >> 6;
  int wr = w >> 1, wc = w & 1;
  int m16 = lane & 15, quad = lane >> 4;
  int rb = blockIdx.x;
  int row0 = rb * BM, col0 = 0;
  int srow = lane >> 2, scol8 = (lane & 3) * 8;

  {  // compute BN1 scale/shift for this thread's channel (C1 == blockDim)
    const float invBN = 1.0f / (float)BN_TOTAL;
    float mean = sum1[tid] * invBN;
    float var = sumsq1[tid] * invBN - mean * mean;
    float sc = g1[tid] / sqrtf(var + 1e-5f);
    scs[tid] = sc;
    shs[tid] = beta1[tid] - mean * sc;
  }

  f32x4 acc[4][4];
#pragma unroll
  for (int j = 0; j < 4; j++) {
    float bj = bias[col0 + wc * 64 + j * 16 + m16];
#pragma unroll
    for (int i = 0; i < 4; i++) acc[i][j] = f32x4{bj, bj, bj, bj};
  }
  __syncthreads();

  for (int k0 = 0; k0 < C1; k0 += BK) {
#pragma unroll
    for (int kq = 0; kq < 2; kq++) {
      int ar = 32 * w + 16 * kq + srow;
      int lb = __builtin_amdgcn_readfirstlane((32 * w + 16 * kq) * BK);
      gld_lds16(&W2h[(size_t)(col0 + ar) * C1 + k0 + scol8], &Bs[lb]);
      // A tile: load Y1, apply BN1+ReLU, write LDS
      s16x8 v = *(const s16x8*)&Y1[(size_t)(row0 + ar) * C1 + k0 + scol8];
      unsigned short ov[8];
#pragma unroll
      for (int e = 0; e < 8; e++) {
        float x = bf2f((unsigned short)v[e]);
        float y = fmaxf(fmaf(x, scs[k0 + scol8 + e], shs[k0 + scol8 + e]), 0.f);
        ov[e] = f2bf(y);
      }
      *(s16x8*)&As[ar * BK + scol8] = *(const s16x8*)ov;
    }
    __syncthreads();

    bf16x8 a[4], bb[4];
#pragma unroll
    for (int i = 0; i < 4; i++)
      a[i] = __builtin_bit_cast(bf16x8,
          *(const s16x8*)&As[(wr * 64 + i * 16 + m16) * BK + quad * 8]);
#pragma unroll
    for (int j = 0; j < 4; j++)
      bb[j] = __builtin_bit_cast(bf16x8,
          *(const s16x8*)&Bs[(wc * 64 + j * 16 + m16) * BK + quad * 8]);
#pragma unroll
    for (int i = 0; i < 4; i++)
#pragma unroll
      for (int j = 0; j < 4; j++)
        acc[i][j] = __builtin_amdgcn_mfma_f32_16x16x32_bf16(a[i], bb[j], acc[i][j], 0, 0, 0);
    __syncthreads();
  }

#pragma unroll
  for (int j = 0; j < 4; j++) {
    int col = col0 + wc * 64 + j * 16 + m16;
    float s = 0.f, q = 0.f;
#pragma unroll
    for (int i = 0; i < 4; i++)
#pragma unroll
      for (int r = 0; r < 4; r++) {
        float v = acc[i][j][r];
        Y2[(size_t)(row0 + wr * 64 + i * 16 + quad * 4 + r) * C2 + col] = f2bf(v);
        s += v; q = fmaf(v, v, q);
      }
    s += __shfl_xor(s, 16, 64); s += __shfl_xor(s, 32, 64);
    q += __shfl_xor(q, 16, 64); q += __shfl_xor(q, 32, 64);
    if (quad == 0) {
      atomicAdd(&sum2[col], s);
      atomicAdd(&sumsq2[col], q);
    }
  }
}

// ---------------------------------------------------------------------------
// Final: out[b][c][n] = relu(bn2(Y2)) transposed, fp32 out.
// ---------------------------------------------------------------------------
__global__ void final_kernel(const unsigned short* __restrict__ Y2,
                             const float* __restrict__ sum2,
                             const float* __restrict__ sumsq2,
                             const float* __restrict__ g2,
                             const float* __restrict__ beta2,
                             float* __restrict__ out) {
  __shared__ float tile[32][33];
  int b = blockIdx.z;
  int n0 = blockIdx.x * 32;
  int c0 = blockIdx.y * 32;
  int tx = threadIdx.x, ty = threadIdx.y;
  int c = c0 + tx;
  const float invBN = 1.0f / (float)BN_TOTAL;
  float mean = sum2[c] * invBN;
  float var = sumsq2[c] * invBN - mean * mean;
  float sc = g2[c] / sqrtf(var + 1e-5f);
  float sh = beta2[c] - mean * sc;
#pragma unroll
  for (int i = 0; i < 32; i += 8) {
    int n = n0 + ty + i;
    float v = bf2f(Y2[((size_t)b * NPT + n) * C2 + c0 + tx]);
    tile[ty + i][tx] = fmaxf(fmaf(v, sc, sh), 0.f);
  }
  __syncthreads();
#pragma unroll
  for (int i = 0; i < 32; i += 8) {
    int cc = c0 + ty + i;
    out[((size_t)b * C2 + cc) * NPT + n0 + tx] = tile[tx][ty + i];
  }
}

// ---------------------------------------------------------------------------
extern "C" void kernel_launch(void* const* d_in, const int* in_sizes, int n_in,
                              void* d_out, int out_size, void* d_ws, size_t ws_size,
                              hipStream_t stream) {
  (void)in_sizes; (void)n_in; (void)out_size; (void)ws_size;
  const float* pos   = (const float*)d_in[0];
  const float* spos  = (const float*)d_in[1];
  const float* skip  = (const float*)d_in[2];
  const float* sfeat = (const float*)d_in[3];
  const float* W1    = (const float*)d_in[4];
  const float* b1    = (const float*)d_in[5];
  const float* g1    = (const float*)d_in[6];
  const float* beta1 = (const float*)d_in[7];
  const float* W2    = (const float*)d_in[8];
  const float* b2    = (const float*)d_in[9];
  const float* g2    = (const float*)d_in[10];
  const float* beta2 = (const float*)d_in[11];
  float* out = (float*)d_out;

  float* ws = (float*)d_ws;
  size_t off = 0;
  float* sfeatT  = ws + off; off += (size_t)BATCH * NSMP * D2C;
  unsigned short* featB = (unsigned short*)(ws + off); off += (size_t)BN_TOTAL * CIN / 2;
  unsigned short* Y1    = (unsigned short*)(ws + off); off += (size_t)BN_TOTAL * C1 / 2;
  unsigned short* Y2    = (unsigned short*)(ws + off); off += (size_t)BN_TOTAL * C2 / 2;
  unsigned short* W1h   = (unsigned short*)(ws + off); off += (size_t)C1 * CIN / 2;
  unsigned short* W2h   = (unsigned short*)(ws + off); off += (size_t)C2 * C1 / 2;
  float* sposI   = ws + off; off += (size_t)BATCH * NSMP * 3;
  float4* qs4    = (float4*)(ws + off); off += (size_t)BATCH * NSMP * 4;
  float* mkG     = ws + off; off += (size_t)32 * BN_TOTAL;   // 8.4 MB
  float* stats   = ws + off; off += 1024;
  float* sum1   = stats;        // [256]
  float* sumsq1 = stats + 256;  // [256]
  float* sum2   = stats + 512;  // [128]
  float* sumsq2 = stats + 640;  // [128]

  prep_all<<<PT_T + PT_S + PT_M, 256, 0, stream>>>(
      sfeat, sfeatT, skip, featB, spos, sposI, qs4, W1, W1h, W2, W2h, stats);

  knn_scan<<<BN_TOTAL / 256, 512, 0, stream>>>(pos, qs4, mkG);

  knn_post<<<BN_TOTAL / (PPW * 4), 256, 0, stream>>>(pos, sposI, mkG, sfeatT, featB);

  gemm1_mw<<<NRB, 512, 0, stream>>>(featB, W1h, b1, Y1, sum1, sumsq1);

  gemm2_mw<<<NRB, 256, 0, stream>>>(
      Y1, g1, beta1, sum1, sumsq1, W2h, b2, Y2, sum2, sumsq2);

  final_kernel<<<dim3(NPT / 32, C2 / 32, BATCH), dim3(32, 8), 0, stream>>>(
      Y2, sum2, sumsq2, g2, beta2, out);
}

// Round 13
// 284.647 us; speedup vs baseline: 1.1082x; 1.1082x over previous
//
#include <hip/hip_runtime.h>

// Problem constants
constexpr int BATCH = 8;
constexpr int NPT   = 8192;   // N points
constexpr int NSMP  = 2048;   // S sampled points
constexpr int D1C   = 128;    // skip feature channels
constexpr int D2C   = 256;    // sampled feature channels
constexpr int CIN   = 384;    // D1C + D2C
constexpr int C1    = 256;    // layer-1 out channels
constexpr int C2    = 128;    // layer-2 out channels
constexpr int BN_TOTAL = BATCH * NPT;  // 65536 rows

constexpr int BM = 128, BK = 32;
constexpr int NRB = BN_TOTAL / BM;   // 512 row-blocks

typedef __bf16 bf16x8 __attribute__((ext_vector_type(8)));
typedef short  s16x8  __attribute__((ext_vector_type(8)));
typedef float  f32x4  __attribute__((ext_vector_type(4)));
typedef unsigned short u16x4 __attribute__((ext_vector_type(4)));

__device__ __forceinline__ unsigned short f2bf(float x) {
  unsigned u = __builtin_bit_cast(unsigned, x);
  u += 0x7fffu + ((u >> 16) & 1u);   // round-to-nearest-even
  return (unsigned short)(u >> 16);
}
__device__ __forceinline__ float bf2f(unsigned short h) {
  return __builtin_bit_cast(float, (unsigned)h << 16);
}

// async global -> LDS, 16 B per lane; lds dest wave-uniform base + lane*16
__device__ __forceinline__ void gld_lds16(const void* g, void* l) {
  __builtin_amdgcn_global_load_lds(
      (const __attribute__((address_space(1))) void*)g,
      (__attribute__((address_space(3))) void*)l, 16, 0, 0);
}

// ---------------------------------------------------------------------------
// prep_all: fused transpose(sfeat->sfeatT) + skip->featB + W casts + spos pack
// + BN-stat zeroing. Role selected by block-index range.
// R5 lesson: NO __threadfence cross-block reductions on CDNA4; BN stats go
// through device-scope float atomics (G12).
// ---------------------------------------------------------------------------
constexpr int PT_T = (NSMP / 32) * (D2C / 32) * BATCH;  // 4096 transpose blocks
constexpr int PT_S = (NPT / 32) * (D1C / 32) * BATCH;   // 8192 skip blocks
constexpr int PT_M = (C1 * CIN + 255) / 256;            // 384 misc blocks

__global__ __launch_bounds__(256) void prep_all(
    const float* __restrict__ sfeat, float* __restrict__ sfeatT,
    const float* __restrict__ skip, unsigned short* __restrict__ featB,
    const float* __restrict__ spos, float* __restrict__ sposI,
    float4* __restrict__ qs4,
    const float* __restrict__ W1, unsigned short* __restrict__ W1h,
    const float* __restrict__ W2, unsigned short* __restrict__ W2h,
    float* __restrict__ stats) {
  __shared__ float tile[32][33];
  int bid = blockIdx.x, tid = threadIdx.x;
  int tx = tid & 31, ty = tid >> 5;
  if (bid < PT_T) {
    int z = bid >> 9;
    int r = bid & 511;
    int c0 = (r & 63) * 32;     // over NSMP
    int r0 = (r >> 6) * 32;     // over D2C
    const float* inb = sfeat + (size_t)z * D2C * NSMP;
    float* outb = sfeatT + (size_t)z * NSMP * D2C;
#pragma unroll
    for (int i = 0; i < 32; i += 8)
      tile[ty + i][tx] = inb[(size_t)(r0 + ty + i) * NSMP + c0 + tx];
    __syncthreads();
#pragma unroll
    for (int i = 0; i < 32; i += 8)
      outb[(size_t)(c0 + ty + i) * D2C + r0 + tx] = tile[tx][ty + i];
  } else if (bid < PT_T + PT_S) {
    int id = bid - PT_T;
    int z = id >> 10;
    int r = id & 1023;
    int n0 = (r & 255) * 32;    // over NPT
    int d0 = (r >> 8) * 32;     // over D1C
#pragma unroll
    for (int i = 0; i < 32; i += 8)
      tile[ty + i][tx] = skip[((size_t)z * D1C + d0 + ty + i) * NPT + n0 + tx];
    __syncthreads();
#pragma unroll
    for (int i = 0; i < 32; i += 8) {
      int n = n0 + ty + i;
      featB[((size_t)z * NPT + n) * CIN + d0 + tx] = f2bf(tile[tx][ty + i]);
    }
  } else {
    int g = (bid - PT_T - PT_S) * 256 + tid;
    if (g < 768) stats[g] = 0.f;
    if (g < C1 * CIN) W1h[g] = f2bf(W1[g]);
    if (g < C2 * C1)  W2h[g] = f2bf(W2[g]);
    if (g < BATCH * NSMP) {
      int b = g >> 11, s = g & (NSMP - 1);
      const float* sp = spos + (size_t)b * 3 * NSMP;
      float x = sp[s], y = sp[NSMP + s], z = sp[2 * NSMP + s];
      sposI[(size_t)g * 3 + 0] = x;
      sposI[(size_t)g * 3 + 1] = y;
      sposI[(size_t)g * 3 + 2] = z;
      qs4[g] = make_float4(-2.f * x, -2.f * y, -2.f * z,
                           fmaf(x, x, fmaf(y, y, z * z)));
    }
  }
}

// ---------------------------------------------------------------------------
// knn_all (R8 monolith + halved-qs staging for 4 blocks/CU):
// R9/R11/R12 lesson: splitting scan/post loses (post is a gather-latency
// chain; mkG round-trip adds 50MB). R7->R8 lesson: blocks/CU is the lever
// (1->2 blk/CU = 90->82.8us). This version: candidate set staged in TWO
// 16KB halves — each wave restages only its OWN 2KB segment (no cross-wave
// reads -> NO block barrier between halves; per-wave lgkmcnt(0)+sched_barrier
// before overwrite per rule #18, vmcnt(0) after issue). LDS 36.9 -> ~19.6KB
// -> launch_bounds(512,4): 4 blocks/CU, 32 waves = full occupancy.
// Retained: XCD swizzle b=blk&7 (R7-proven), LDS broadcast scan (R4),
// +pp recenter (R2), mk reuse of the wave's dead segment.
// ---------------------------------------------------------------------------
constexpr int KWAVES = 8;
constexpr int QHALF = NSMP / 2;        // 1024 candidates per half (16 KB)
constexpr int SEGH  = QHALF / KWAVES;  // 128 candidates per wave per half
constexpr int PPB   = 128;             // points per block

__device__ __forceinline__ void ins_med3(float kf, float& k0, float& k1,
                                         float& k2, float& k3) {
  float o0 = k0, o1 = k1, o2 = k2;
  k0 = fminf(kf, o0);
  k1 = __builtin_amdgcn_fmed3f(kf, o0, o1);
  k2 = __builtin_amdgcn_fmed3f(kf, o1, o2);
  k3 = __builtin_amdgcn_fmed3f(kf, o2, k3);
}

__device__ __forceinline__ bool dless(double d, int i, double D, int I) {
  return d < D || (d == D && i < I);
}
__device__ __forceinline__ void dins3(double d, int i,
                                      double& b0, double& b1, double& b2,
                                      int& i0, int& i1, int& i2) {
  if (dless(d, i, b2, i2)) {
    if (dless(d, i, b1, i1)) {
      b2 = b1; i2 = i1;
      if (dless(d, i, b0, i0)) { b1 = b0; i1 = i0; b0 = d; i0 = i; }
      else                     { b1 = d; i1 = i; }
    } else { b2 = d; i2 = i; }
  }
}

__global__ __launch_bounds__(512, 4) void knn_all(
    const float* __restrict__ pos,    // [B,3,NPT]
    const float4* __restrict__ qs4g,  // [B,NSMP] transformed
    const float* __restrict__ sposI,  // [B,NSMP,3] original (fp64 paths)
    const float* __restrict__ sfeatT, // [B,NSMP,D2C]
    unsigned short* __restrict__ featB) {
  // 16 KB: qs halves double as per-wave mk storage (wave's own dead 2KB seg)
  __shared__ __align__(16) unsigned char smem[QHALF * 16];
  float4* qs  = (float4*)smem;
  float*  mkf = (float*)smem;
#define MKF(w, sl, m, l) mkf[(w) * 512 + ((sl) * 2 + (m)) * 64 + (l)]
  __shared__ int   il[PPB][3];
  __shared__ float wl[PPB][3];
  __shared__ int   fl[PPB];
  __shared__ int   fcnt;

  int tid = threadIdx.x;
  int wave = tid >> 6, lane = tid & 63;
  int blk = blockIdx.x;
  int b = blk & 7;               // XCD swizzle: batch b -> XCD b
  int n0 = (blk >> 3) * PPB;     // 64 chunks of 128 points per batch

  if (tid == 0) fcnt = 0;

  const float* pb = pos + (size_t)b * 3 * NPT;
  float px[2], py[2], pz[2], pp[2];
#pragma unroll
  for (int m = 0; m < 2; m++) {
    int n = n0 + (m << 6) + lane;
    px[m] = pb[n]; py[m] = pb[NPT + n]; pz[m] = pb[2 * NPT + n];
    pp[m] = fmaf(px[m], px[m], fmaf(py[m], py[m], pz[m] * pz[m]));
  }

  const float INF = __builtin_inff();
  float k0[2], k1[2], k2[2], k3[2];
#pragma unroll
  for (int m = 0; m < 2; m++) { k0[m] = INF; k1[m] = INF; k2[m] = INF; k3[m] = INF; }

  int segBase = wave * SEGH;     // this wave's 2 KB region in qs
  const float4* qsrc = qs4g + (size_t)b * NSMP;

#define KSTEP2(Q, SS)                                                        \
  {                                                                          \
    _Pragma("unroll")                                                        \
    for (int m_ = 0; m_ < 2; m_++) {                                         \
      float tt = (Q).w + pp[m_];  /* recenter: d small near neighbors */     \
      float d_ = fmaf(px[m_], (Q).x,                                         \
                      fmaf(py[m_], (Q).y, fmaf(pz[m_], (Q).z, tt)));         \
      unsigned ki_ = (__builtin_bit_cast(unsigned, d_) & 0xFFFFF800u) |      \
                     (unsigned)(SS);                                         \
      ins_med3(__builtin_bit_cast(float, ki_), k0[m_], k1[m_], k2[m_], k3[m_]); \
    }                                                                        \
  }

#pragma unroll
  for (int h = 0; h < 2; h++) {
    int gbase = h * QHALF + wave * SEGH;  // global candidate base this round
    if (h) {
      // wave-local: all my ds_reads of the old half must retire before the
      // async LDS writes land in my segment (rule #18: pin with sched_barrier)
      asm volatile("s_waitcnt lgkmcnt(0)" ::: "memory");
      __builtin_amdgcn_sched_barrier(0);
    }
#pragma unroll
    for (int r = 0; r < 2; r++)
      gld_lds16(&qsrc[gbase + r * 64 + lane], &qs[segBase + r * 64]);
    asm volatile("s_waitcnt vmcnt(0)" ::: "memory");  // my LDS writes visible
    __builtin_amdgcn_sched_barrier(0);

    for (int t = 0; t < SEGH; t += 8) {
      float4 qv[8];
#pragma unroll
      for (int u = 0; u < 8; u++) qv[u] = qs[segBase + t + u];  // broadcast
#pragma unroll
      for (int u = 0; u < 8; u++) KSTEP2(qv[u], gbase + t + u)
    }
  }
#undef KSTEP2

  // write per-wave top-4 into own (dead) segment
  asm volatile("s_waitcnt lgkmcnt(0)" ::: "memory");
  __builtin_amdgcn_sched_barrier(0);
#pragma unroll
  for (int m = 0; m < 2; m++) {
    MKF(wave, 0, m, lane) = k0[m];
    MKF(wave, 1, m, lane) = k1[m];
    MKF(wave, 2, m, lane) = k2[m];
    MKF(wave, 3, m, lane) = k3[m];
  }
  __syncthreads();

  // ---- per-point finalize (PPB threads), flag + fp64 weights into LDS ----
  if (tid < PPB) {
    int pm = tid >> 6, pl = tid & 63;
    float K0 = INF, K1 = INF, K2 = INF, K3 = INF;
#pragma unroll
    for (int w = 0; w < KWAVES; w++)
#pragma unroll
      for (int sl = 0; sl < 4; sl++)
        ins_med3(MKF(w, sl, pm, pl), K0, K1, K2, K3);

    int I0 = (int)(__builtin_bit_cast(unsigned, K0) & 0x7FFu);
    int I1 = (int)(__builtin_bit_cast(unsigned, K1) & 0x7FFu);
    int I2 = (int)(__builtin_bit_cast(unsigned, K2) & 0x7FFu);
    float d2m = __builtin_bit_cast(float, __builtin_bit_cast(unsigned, K2) & 0xFFFFF800u);
    float d3m = __builtin_bit_cast(float, __builtin_bit_cast(unsigned, K3) & 0xFFFFF800u);
    bool flag = (d3m - d2m) < 2e-3f * fmaxf(d3m, 0.f) + 1e-5f;
    if (flag) {
      int slot = atomicAdd(&fcnt, 1);
      fl[slot] = tid;
    }
    int n = n0 + tid;
    const float* q = sposI + (size_t)b * 3 * NSMP;
    double pxd = (double)pb[n], pyd = (double)pb[NPT + n], pzd = (double)pb[2 * NPT + n];
    double dd[3]; int II[3] = {I0, I1, I2};
#pragma unroll
    for (int k = 0; k < 3; k++) {
      double dx = pxd - (double)q[3 * II[k]];
      double dy = pyd - (double)q[3 * II[k] + 1];
      double dz = pzd - (double)q[3 * II[k] + 2];
      dd[k] = dx * dx + dy * dy + dz * dz;
    }
    double w0 = 1.0 / (dd[0] + 1e-8);
    double w1 = 1.0 / (dd[1] + 1e-8);
    double w2 = 1.0 / (dd[2] + 1e-8);
    double inv = 1.0 / (w0 + w1 + w2);
    il[tid][0] = I0; il[tid][1] = I1; il[tid][2] = I2;
    wl[tid][0] = (float)(w0 * inv);
    wl[tid][1] = (float)(w1 * inv);
    wl[tid][2] = (float)(w2 * inv);
  }
  __syncthreads();

  // ---- exact fp64 fallback for flagged points, one wave per point ----
  int fc = fcnt;
  for (int t = wave; t < fc; t += KWAVES) {
    int P = fl[t];
    int n = n0 + P;
    double pxd = (double)pb[n], pyd = (double)pb[NPT + n], pzd = (double)pb[2 * NPT + n];
    const float* q = sposI + (size_t)b * 3 * NSMP;
    double b0 = 1e300, b1 = 1e300, b2 = 1e300;
    int i0 = 0x7FFFFFFF, i1 = 0x7FFFFFFF, i2 = 0x7FFFFFFF;
    for (int s = lane; s < NSMP; s += 64) {
      double dx = pxd - (double)q[3 * s];
      double dy = pyd - (double)q[3 * s + 1];
      double dz = pzd - (double)q[3 * s + 2];
      double d = dx * dx + dy * dy + dz * dz;
      dins3(d, s, b0, b1, b2, i0, i1, i2);
    }
#pragma unroll
    for (int m = 1; m < 64; m <<= 1) {
      double o0 = __shfl_xor(b0, m, 64), o1 = __shfl_xor(b1, m, 64), o2 = __shfl_xor(b2, m, 64);
      int    j0 = __shfl_xor(i0, m, 64), j1 = __shfl_xor(i1, m, 64), j2 = __shfl_xor(i2, m, 64);
      dins3(o0, j0, b0, b1, b2, i0, i1, i2);
      dins3(o1, j1, b0, b1, b2, i0, i1, i2);
      dins3(o2, j2, b0, b1, b2, i0, i1, i2);
    }
    if (lane == 0) {
      double w0 = 1.0 / (b0 + 1e-8);
      double w1 = 1.0 / (b1 + 1e-8);
      double w2 = 1.0 / (b2 + 1e-8);
      double inv = 1.0 / (w0 + w1 + w2);
      il[P][0] = i0; il[P][1] = i1; il[P][2] = i2;
      wl[P][0] = (float)(w0 * inv);
      wl[P][1] = (float)(w1 * inv);
      wl[P][2] = (float)(w2 * inv);
    }
  }
  __syncthreads();

  // ---- interp: wave handles 16 points, 2/iter with 6 pre-issued gathers ----
  const float* base = sfeatT + (size_t)b * NSMP * D2C;
  for (int i = 0; i < 16; i += 2) {
    int P0 = (wave << 4) + i, P1 = P0 + 1;
    int a0 = il[P0][0], a1 = il[P0][1], a2 = il[P0][2];
    int c0 = il[P1][0], c1 = il[P1][1], c2 = il[P1][2];
    float aw0 = wl[P0][0], aw1 = wl[P0][1], aw2 = wl[P0][2];
    float cw0 = wl[P1][0], cw1 = wl[P1][1], cw2 = wl[P1][2];
    float4 u0 = *(const float4*)&base[(size_t)a0 * D2C + (lane << 2)];
    float4 u1 = *(const float4*)&base[(size_t)a1 * D2C + (lane << 2)];
    float4 u2 = *(const float4*)&base[(size_t)a2 * D2C + (lane << 2)];
    float4 v0 = *(const float4*)&base[(size_t)c0 * D2C + (lane << 2)];
    float4 v1 = *(const float4*)&base[(size_t)c1 * D2C + (lane << 2)];
    float4 v2 = *(const float4*)&base[(size_t)c2 * D2C + (lane << 2)];
    u16x4 o0, o1;
    o0[0] = f2bf(aw0 * u0.x + aw1 * u1.x + aw2 * u2.x);
    o0[1] = f2bf(aw0 * u0.y + aw1 * u1.y + aw2 * u2.y);
    o0[2] = f2bf(aw0 * u0.z + aw1 * u1.z + aw2 * u2.z);
    o0[3] = f2bf(aw0 * u0.w + aw1 * u1.w + aw2 * u2.w);
    o1[0] = f2bf(cw0 * v0.x + cw1 * v1.x + cw2 * v2.x);
    o1[1] = f2bf(cw0 * v0.y + cw1 * v1.y + cw2 * v2.y);
    o1[2] = f2bf(cw0 * v0.z + cw1 * v1.z + cw2 * v2.z);
    o1[3] = f2bf(cw0 * v0.w + cw1 * v1.w + cw2 * v2.w);
    *(u16x4*)&featB[((size_t)b * NPT + n0 + P0) * CIN + D1C + (lane << 2)] = o0;
    *(u16x4*)&featB[((size_t)b * NPT + n0 + P1) * CIN + D1C + (lane << 2)] = o1;
  }
#undef MKF
}

// ---------------------------------------------------------------------------
// GEMM1 (R10, measured equal-best): 8-wave 128x256 full-width tile.
// featB read once per row-tile. BN1 stats via device-scope float atomics.
// ---------------------------------------------------------------------------
__global__ __launch_bounds__(512) void gemm1_mw(
    const unsigned short* __restrict__ featB,  // [BN_TOTAL][CIN] bf16
    const unsigned short* __restrict__ W1h,    // [C1][CIN] bf16
    const float* __restrict__ bias,
    unsigned short* __restrict__ Y1,           // [BN_TOTAL][C1] bf16
    float* __restrict__ sum1,                  // [C1]
    float* __restrict__ sumsq1) {              // [C1]
  __shared__ __align__(16) unsigned short As[BM * BK];  // 8 KB
  __shared__ __align__(16) unsigned short Bs[C1 * BK];  // 16 KB
  int tid = threadIdx.x;
  int lane = tid & 63, w = tid >> 6;
  int wr = w >> 2, wc = w & 3;
  int m16 = lane & 15, quad = lane >> 4;
  int rb = blockIdx.x;
  int row0 = rb * BM;
  int srow = lane >> 2, scol8 = (lane & 3) * 8;

  f32x4 acc[4][4];
#pragma unroll
  for (int j = 0; j < 4; j++) {
    float bj = bias[wc * 64 + j * 16 + m16];
#pragma unroll
    for (int i = 0; i < 4; i++) acc[i][j] = f32x4{bj, bj, bj, bj};
  }

  for (int k0 = 0; k0 < CIN; k0 += BK) {
    {  // A tile: 128x32, one round (8 waves x 16 rows)
      int lb = __builtin_amdgcn_readfirstlane((w * 16) * BK);
      gld_lds16(&featB[(size_t)(row0 + w * 16 + srow) * CIN + k0 + scol8],
                &As[lb]);
    }
#pragma unroll
    for (int rr = 0; rr < 2; rr++) {  // B tile: 256x32, two rounds
      int lb = __builtin_amdgcn_readfirstlane((rr * 128 + w * 16) * BK);
      gld_lds16(&W1h[(size_t)(rr * 128 + w * 16 + srow) * CIN + k0 + scol8],
                &Bs[lb]);
    }
    __syncthreads();

    bf16x8 a[4], bb[4];
#pragma unroll
    for (int i = 0; i < 4; i++)
      a[i] = __builtin_bit_cast(bf16x8,
          *(const s16x8*)&As[(wr * 64 + i * 16 + m16) * BK + quad * 8]);
#pragma unroll
    for (int j = 0; j < 4; j++)
      bb[j] = __builtin_bit_cast(bf16x8,
          *(const s16x8*)&Bs[(wc * 64 + j * 16 + m16) * BK + quad * 8]);
#pragma unroll
    for (int i = 0; i < 4; i++)
#pragma unroll
      for (int j = 0; j < 4; j++)
        acc[i][j] = __builtin_amdgcn_mfma_f32_16x16x32_bf16(a[i], bb[j], acc[i][j], 0, 0, 0);
    __syncthreads();
  }

#pragma unroll
  for (int j = 0; j < 4; j++) {
    int col = wc * 64 + j * 16 + m16;
    float s = 0.f, q = 0.f;
#pragma unroll
    for (int i = 0; i < 4; i++)
#pragma unroll
      for (int r = 0; r < 4; r++) {
        float v = acc[i][j][r];
        Y1[(size_t)(row0 + wr * 64 + i * 16 + quad * 4 + r) * C1 + col] = f2bf(v);
        s += v; q = fmaf(v, v, q);
      }
    s += __shfl_xor(s, 16, 64); s += __shfl_xor(s, 32, 64);
    q += __shfl_xor(q, 16, 64); q += __shfl_xor(q, 32, 64);
    if (quad == 0) {
      atomicAdd(&sum1[col], s);
      atomicAdd(&sumsq1[col], q);
    }
  }
}

// ---------------------------------------------------------------------------
// GEMM2, 4-wave 128x128 tile: X2 = relu(bn1(Y1)) fused in reg-staged A.
// BN1 coefficients computed in-kernel from atomic sums (stream order).
// BN2 stats via atomics. grid = NRB.
// ---------------------------------------------------------------------------
__global__ __launch_bounds__(256) void gemm2_mw(
    const unsigned short* __restrict__ Y1,   // [BN_TOTAL][C1] bf16
    const float* __restrict__ g1, const float* __restrict__ beta1,
    const float* __restrict__ sum1, const float* __restrict__ sumsq1,
    const unsigned short* __restrict__ W2h,  // [C2][C1] bf16
    const float* __restrict__ bias,
    unsigned short* __restrict__ Y2,         // [BN_TOTAL][C2] bf16
    float* __restrict__ sum2, float* __restrict__ sumsq2) {
  __shared__ __align__(16) unsigned short As[BM * BK];
  __shared__ __align__(16) unsigned short Bs[BM * BK];
  __shared__ float scs[C1], shs[C1];
  int tid = threadIdx.x;
  int lane = tid & 63, w = tid >> 6;
  int wr = w >> 1, wc = w & 1;
  int m16 = lane & 15, quad = lane >> 4;
  int rb = blockIdx.x;
  int row0 = rb * BM, col0 = 0;
  int srow = lane >> 2, scol8 = (lane & 3) * 8;

  {  // compute BN1 scale/shift for this thread's channel (C1 == blockDim)
    const float invBN = 1.0f / (float)BN_TOTAL;
    float mean = sum1[tid] * invBN;
    float var = sumsq1[tid] * invBN - mean * mean;
    float sc = g1[tid] / sqrtf(var + 1e-5f);
    scs[tid] = sc;
    shs[tid] = beta1[tid] - mean * sc;
  }

  f32x4 acc[4][4];
#pragma unroll
  for (int j = 0; j < 4; j++) {
    float bj = bias[col0 + wc * 64 + j * 16 + m16];
#pragma unroll
    for (int i = 0; i < 4; i++) acc[i][j] = f32x4{bj, bj, bj, bj};
  }
  __syncthreads();

  for (int k0 = 0; k0 < C1; k0 += BK) {
#pragma unroll
    for (int kq = 0; kq < 2; kq++) {
      int ar = 32 * w + 16 * kq + srow;
      int lb = __builtin_amdgcn_readfirstlane((32 * w + 16 * kq) * BK);
      gld_lds16(&W2h[(size_t)(col0 + ar) * C1 + k0 + scol8], &Bs[lb]);
      // A tile: load Y1, apply BN1+ReLU, write LDS
      s16x8 v = *(const s16x8*)&Y1[(size_t)(row0 + ar) * C1 + k0 + scol8];
      unsigned short ov[8];
#pragma unroll
      for (int e = 0; e < 8; e++) {
        float x = bf2f((unsigned short)v[e]);
        float y = fmaxf(fmaf(x, scs[k0 + scol8 + e], shs[k0 + scol8 + e]), 0.f);
        ov[e] = f2bf(y);
      }
      *(s16x8*)&As[ar * BK + scol8] = *(const s16x8*)ov;
    }
    __syncthreads();

    bf16x8 a[4], bb[4];
#pragma unroll
    for (int i = 0; i < 4; i++)
      a[i] = __builtin_bit_cast(bf16x8,
          *(const s16x8*)&As[(wr * 64 + i * 16 + m16) * BK + quad * 8]);
#pragma unroll
    for (int j = 0; j < 4; j++)
      bb[j] = __builtin_bit_cast(bf16x8,
          *(const s16x8*)&Bs[(wc * 64 + j * 16 + m16) * BK + quad * 8]);
#pragma unroll
    for (int i = 0; i < 4; i++)
#pragma unroll
      for (int j = 0; j < 4; j++)
        acc[i][j] = __builtin_amdgcn_mfma_f32_16x16x32_bf16(a[i], bb[j], acc[i][j], 0, 0, 0);
    __syncthreads();
  }

#pragma unroll
  for (int j = 0; j < 4; j++) {
    int col = col0 + wc * 64 + j * 16 + m16;
    float s = 0.f, q = 0.f;
#pragma unroll
    for (int i = 0; i < 4; i++)
#pragma unroll
      for (int r = 0; r < 4; r++) {
        float v = acc[i][j][r];
        Y2[(size_t)(row0 + wr * 64 + i * 16 + quad * 4 + r) * C2 + col] = f2bf(v);
        s += v; q = fmaf(v, v, q);
      }
    s += __shfl_xor(s, 16, 64); s += __shfl_xor(s, 32, 64);
    q += __shfl_xor(q, 16, 64); q += __shfl_xor(q, 32, 64);
    if (quad == 0) {
      atomicAdd(&sum2[col], s);
      atomicAdd(&sumsq2[col], q);
    }
  }
}

// ---------------------------------------------------------------------------
// Final: out[b][c][n] = relu(bn2(Y2)) transposed, fp32 out.
// ---------------------------------------------------------------------------
__global__ void final_kernel(const unsigned short* __restrict__ Y2,
                             const float* __restrict__ sum2,
                             const float* __restrict__ sumsq2,
                             const float* __restrict__ g2,
                             const float* __restrict__ beta2,
                             float* __restrict__ out) {
  __shared__ float tile[32][33];
  int b = blockIdx.z;
  int n0 = blockIdx.x * 32;
  int c0 = blockIdx.y * 32;
  int tx = threadIdx.x, ty = threadIdx.y;
  int c = c0 + tx;
  const float invBN = 1.0f / (float)BN_TOTAL;
  float mean = sum2[c] * invBN;
  float var = sumsq2[c] * invBN - mean * mean;
  float sc = g2[c] / sqrtf(var + 1e-5f);
  float sh = beta2[c] - mean * sc;
#pragma unroll
  for (int i = 0; i < 32; i += 8) {
    int n = n0 + ty + i;
    float v = bf2f(Y2[((size_t)b * NPT + n) * C2 + c0 + tx]);
    tile[ty + i][tx] = fmaxf(fmaf(v, sc, sh), 0.f);
  }
  __syncthreads();
#pragma unroll
  for (int i = 0; i < 32; i += 8) {
    int cc = c0 + ty + i;
    out[((size_t)b * C2 + cc) * NPT + n0 + tx] = tile[tx][ty + i];
  }
}

// ---------------------------------------------------------------------------
extern "C" void kernel_launch(void* const* d_in, const int* in_sizes, int n_in,
                              void* d_out, int out_size, void* d_ws, size_t ws_size,
                              hipStream_t stream) {
  (void)in_sizes; (void)n_in; (void)out_size; (void)ws_size;
  const float* pos   = (const float*)d_in[0];
  const float* spos  = (const float*)d_in[1];
  const float* skip  = (const float*)d_in[2];
  const float* sfeat = (const float*)d_in[3];
  const float* W1    = (const float*)d_in[4];
  const float* b1    = (const float*)d_in[5];
  const float* g1    = (const float*)d_in[6];
  const float* beta1 = (const float*)d_in[7];
  const float* W2    = (const float*)d_in[8];
  const float* b2    = (const float*)d_in[9];
  const float* g2    = (const float*)d_in[10];
  const float* beta2 = (const float*)d_in[11];
  float* out = (float*)d_out;

  float* ws = (float*)d_ws;
  size_t off = 0;
  float* sfeatT  = ws + off; off += (size_t)BATCH * NSMP * D2C;
  unsigned short* featB = (unsigned short*)(ws + off); off += (size_t)BN_TOTAL * CIN / 2;
  unsigned short* Y1    = (unsigned short*)(ws + off); off += (size_t)BN_TOTAL * C1 / 2;
  unsigned short* Y2    = (unsigned short*)(ws + off); off += (size_t)BN_TOTAL * C2 / 2;
  unsigned short* W1h   = (unsigned short*)(ws + off); off += (size_t)C1 * CIN / 2;
  unsigned short* W2h   = (unsigned short*)(ws + off); off += (size_t)C2 * C1 / 2;
  float* sposI   = ws + off; off += (size_t)BATCH * NSMP * 3;
  float4* qs4    = (float4*)(ws + off); off += (size_t)BATCH * NSMP * 4;
  float* stats   = ws + off; off += 1024;
  float* sum1   = stats;        // [256]
  float* sumsq1 = stats + 256;  // [256]
  float* sum2   = stats + 512;  // [128]
  float* sumsq2 = stats + 640;  // [128]

  prep_all<<<PT_T + PT_S + PT_M, 256, 0, stream>>>(
      sfeat, sfeatT, skip, featB, spos, sposI, qs4, W1, W1h, W2, W2h, stats);

  knn_all<<<BN_TOTAL / PPB, 512, 0, stream>>>(pos, qs4, sposI, sfeatT, featB);

  gemm1_mw<<<NRB, 512, 0, stream>>>(featB, W1h, b1, Y1, sum1, sumsq1);

  gemm2_mw<<<NRB, 256, 0, stream>>>(
      Y1, g1, beta1, sum1, sumsq1, W2h, b2, Y2, sum2, sumsq2);

  final_kernel<<<dim3(NPT / 32, C2 / 32, BATCH), dim3(32, 8), 0, stream>>>(
      Y2, sum2, sumsq2, g2, beta2, out);
}